// Round 7
// baseline (132.571 us; speedup 1.0000x reference)
//
#include <hip/hip_runtime.h>
#include <hip/hip_bf16.h>

// x: (N=8, C=512, T=32, H=14, W=14) fp32 contiguous = 131072 rows x 196 floats.
// Single fused kernel. Block b owns 64 consecutive rows (= 2 channels x 32 t,
// one contiguous 50 KB slab). Phase 1 (all 4 waves): quad-scheme GAP (4 threads
// per row, strided float4, shfl_xor combine) -> agent-scope stores to gap[] in
// LLC. __syncthreads (drains stores), thread 0 release-stores flags[b] = V+1
// (V = epoch read from own flag at entry; uniform across blocks invariantly:
// 0xAA poison is uniform, each call does +1 uniformly -> no reset dispatch).
// Phase 2 (wave 0): spin for flags[b-1], flags[b+1] == V+1 (conv over channels
// needs c+-2 = rows +-64, i.e. exactly neighbor blocks), device fence, 5-tap
// conv + sigmoid from LLC, coalesced out write. Bounded spin + fallback
// recompute-from-x makes it deadlock-free and correct regardless of dispatch
// order or flag garbage.

#define F4_PER_ROW 49
#define ROWS_PB 64
#define F4_PB (ROWS_PB * F4_PER_ROW)   // 3136
#define SPIN_MAX 32768

__device__ __forceinline__ float gap_load(const float* gap, int row) {
    return __hip_atomic_load(&gap[row], __ATOMIC_RELAXED, __HIP_MEMORY_SCOPE_AGENT);
}

__device__ __forceinline__ float recompute_gap(const float* __restrict__ x, int row) {
    const float4* pr = reinterpret_cast<const float4*>(x) + (size_t)row * F4_PER_ROW;
    float s = 0.0f;
    for (int i = 0; i < F4_PER_ROW; ++i) {
        float4 u = pr[i];
        s += (u.x + u.y) + (u.z + u.w);
    }
    return s * (1.0f / 196.0f);
}

__global__ __launch_bounds__(256, 8) void fused_attn_kernel(
        const float* __restrict__ x,
        const float* __restrict__ w,
        float* __restrict__ out,
        float* gap,
        unsigned int* flags) {
    const int b   = blockIdx.x;
    const int tid = threadIdx.x;
    const int s   = tid >> 2;   // row within block for GAP, 0..63
    const int q   = tid & 3;    // quad lane

    // Epoch (uniform across all blocks at call entry).
    const unsigned int V =
        __hip_atomic_load(&flags[b], __ATOMIC_RELAXED, __HIP_MEMORY_SCOPE_AGENT);

    // ---- Phase 1: GAP over own contiguous slab (R5 quad scheme) ----
    const float4* p = reinterpret_cast<const float4*>(x) +
                      (size_t)b * F4_PB + s * F4_PER_ROW + q;
    float4 a0 = p[0];
    float4 a1 = p[4];
    #pragma unroll
    for (int i = 2; i < 12; i += 2) {
        float4 u = p[4 * i];
        float4 v = p[4 * (i + 1)];
        a0.x += u.x; a0.y += u.y; a0.z += u.z; a0.w += u.w;
        a1.x += v.x; a1.y += v.y; a1.z += v.z; a1.w += v.w;
    }
    float sum = ((a0.x + a1.x) + (a0.y + a1.y)) + ((a0.z + a1.z) + (a0.w + a1.w));
    if (q == 0) {
        float4 u = p[48];
        sum += (u.x + u.y) + (u.z + u.w);
    }
    sum += __shfl_xor(sum, 1, 64);
    sum += __shfl_xor(sum, 2, 64);

    if (q == 0) {
        __hip_atomic_store(&gap[b * ROWS_PB + s], sum * (1.0f / 196.0f),
                           __ATOMIC_RELAXED, __HIP_MEMORY_SCOPE_AGENT);
    }
    __syncthreads();   // emits s_waitcnt vmcnt(0): all gap stores complete
    if (tid == 0) {
        __threadfence();  // release: gap stores visible before flag
        __hip_atomic_store(&flags[b], V + 1u,
                           __ATOMIC_RELAXED, __HIP_MEMORY_SCOPE_AGENT);
    }

    // ---- Phase 2: wave 0 only ----
    if (tid >= ROWS_PB) return;

    const int c0 = (2 * b) & 511;          // first owned channel (within its n)
    const bool needLo = (c0 != 0);
    const bool needHi = (c0 != 510);
    bool okLo = !needLo, okHi = !needHi;
    for (int it = 0; it < SPIN_MAX && !(okLo && okHi); ++it) {
        if (!okLo)
            okLo = (__hip_atomic_load(&flags[b - 1], __ATOMIC_RELAXED,
                                      __HIP_MEMORY_SCOPE_AGENT) == V + 1u);
        if (!okHi)
            okHi = (__hip_atomic_load(&flags[b + 1], __ATOMIC_RELAXED,
                                      __HIP_MEMORY_SCOPE_AGENT) == V + 1u);
    }
    __threadfence();   // acquire: neighbor gap values ordered after flag reads

    const float w0 = w[0], w1 = w[1], w2 = w[2], w3 = w[3], w4 = w[4];

    const int rr = b * ROWS_PB + tid;      // this thread's output row
    const int cc = c0 + (tid >> 5);        // its channel
    const int lo = b * ROWS_PB, hi = lo + ROWS_PB;

    // Dep fetch: own rows always from LLC; neighbor rows from LLC if flag seen,
    // else recomputed from x (rare fallback; value matches within ulps).
    auto G = [&](int row, bool ok) -> float {
        if (row >= lo && row < hi) return gap_load(gap, row);
        return ok ? gap_load(gap, row) : recompute_gap(x, row);
    };

    float acc = w2 * gap_load(gap, rr);
    if (cc >= 2)   acc += w0 * G(rr - 64, okLo);
    if (cc >= 1)   acc += w1 * G(rr - 32, okLo);
    if (cc <= 510) acc += w3 * G(rr + 32, okHi);
    if (cc <= 509) acc += w4 * G(rr + 64, okHi);

    out[rr] = 1.0f / (1.0f + __expf(-acc));
}

extern "C" void kernel_launch(void* const* d_in, const int* in_sizes, int n_in,
                              void* d_out, int out_size, void* d_ws, size_t ws_size,
                              hipStream_t stream) {
    const float* x = (const float*)d_in[0];   // 8*512*32*14*14
    const float* w = (const float*)d_in[1];   // 5
    float* out = (float*)d_out;               // 8*512*32 = 131072
    float* gap = (float*)d_ws;                // 131072 floats
    unsigned int* flags =
        (unsigned int*)((char*)d_ws + (size_t)131072 * sizeof(float)); // 2048 u32

    const int total_rows = 8 * 512 * 32;          // 131072
    const int blocks = total_rows / ROWS_PB;      // 2048

    fused_attn_kernel<<<blocks, 256, 0, stream>>>(x, w, out, gap, flags);
}